// Round 11
// baseline (281.246 us; speedup 1.0000x reference)
//
#include <hip/hip_runtime.h>

constexpr int R = 3;
constexpr int N = 50000;
constexpr int E = 800000;
constexpr int K = 128;        // IN = HEADS*HID = 128 (both GEMM K dims)
constexpr int NT16 = N / 16;  // 3125 node-tiles for MFMA GEMMs
constexpr int GB = (NT16 + 3) / 4;  // 782 blocks of 4 tiles for GEMMs

// bucketed CSR build
constexpr int BKT_SH = 9;                    // 512 nodes per bucket
constexpr int NBKT = (N + 511) >> 9;         // 98 buckets per relation
constexpr int BCAP = 10240;                  // bucket capacity (avg 8163)
constexpr int P1E = 4096;                    // edges per pass-1 block
constexpr int P1B = (E + P1E - 1) / P1E;     // 196 blocks per relation

// fragment counts for fragment-ordered weights
constexpr int NF1 = 192;   // r(3) x tr(4) x ks(4) x head(2) x hl(2)
constexpr int NF2 = 96;    // t(12) x ks(4) x hl(2)
constexpr int NF3 = 16;    // t(4) x ks(2) x hl(2)

typedef __attribute__((ext_vector_type(8))) short bf16x8;
typedef __attribute__((ext_vector_type(4))) float f32x4;
typedef __attribute__((ext_vector_type(2))) float f32x2;

// ---------------- bf16 helpers (RNE) ----------------

__device__ inline unsigned short f2bf(float f) {
    unsigned u = __float_as_uint(f);
    u += 0x7FFF + ((u >> 16) & 1);
    return (unsigned short)(u >> 16);
}
__device__ inline float bf2f_lo(unsigned p) { return __uint_as_float(p << 16); }
__device__ inline float bf2f_hi(unsigned p) { return __uint_as_float(p & 0xFFFF0000u); }

__device__ inline float lrelu02(float x) { return fmaxf(x, 0.2f * x); }
// fast elu: exp(x)-1 instead of expm1 (error ~1e-6 abs, threshold 3.4e-3)
__device__ inline float elu1f(float x) { return x > 0.f ? x : __expf(x) - 1.f; }

// ---------------- CSR build: pass 1 (bucket scatter, coalesced) ----------------

__global__ __launch_bounds__(256) void bucket_p1(const int* __restrict__ src,
                                                 const int* __restrict__ dst,
                                                 int* __restrict__ gcur,
                                                 uint2* __restrict__ ebuf) {
    __shared__ uint2 img[P1E];                 // 32 KB
    __shared__ int bins[NBKT], bstart[NBKT], gbase[NBKT];
    __shared__ int sc[128];
    const int r = blockIdx.y;
    const int e0 = blockIdx.x * P1E;
    const int cnt = min(P1E, E - e0);
    const int tid = threadIdx.x;
    if (tid < NBKT) bins[tid] = 0;
    __syncthreads();
    int sv[16], dv[16], rk[16];
    int ni = 0;
    for (int i = tid; i < cnt; i += 256, ni++) {
        sv[ni] = src[(size_t)r * E + e0 + i];
        dv[ni] = dst[(size_t)r * E + e0 + i];
        rk[ni] = atomicAdd(&bins[dv[ni] >> BKT_SH], 1);
    }
    __syncthreads();
    if (tid < 128) sc[tid] = (tid < NBKT) ? bins[tid] : 0;
    __syncthreads();
    for (int off = 1; off < 128; off <<= 1) {
        int v = 0;
        if (tid < 128 && tid >= off) v = sc[tid - off];
        __syncthreads();
        if (tid < 128) sc[tid] += v;
        __syncthreads();
    }
    if (tid < NBKT) bstart[tid] = sc[tid] - bins[tid];
    __syncthreads();
    for (int j = 0; j < ni; j++) {
        int b = dv[j] >> BKT_SH;
        img[bstart[b] + rk[j]] = make_uint2((unsigned)sv[j], (unsigned)dv[j]);
    }
    if (tid < NBKT) gbase[tid] = bins[tid] ? atomicAdd(&gcur[r * NBKT + tid], bins[tid]) : 0;
    __syncthreads();
    for (int i = tid; i < cnt; i += 256) {
        uint2 e = img[i];
        int b = (int)(e.y >> BKT_SH);
        int pos = gbase[b] + (i - bstart[b]);
        if (pos < BCAP) ebuf[(size_t)(r * NBKT + b) * BCAP + pos] = e;
    }
}

__global__ void bucket_scan(const int* __restrict__ gcur, int* __restrict__ bpre) {
    int w = threadIdx.x >> 6, lane = threadIdx.x & 63;
    if (w >= R) return;
    const int* g = gcur + w * NBKT;
    int* p = bpre + w * NBKT;
    int carry = 0;
    for (int base = 0; base < NBKT; base += 64) {
        int v = (base + lane < NBKT) ? g[base + lane] : 0;
        int x = v;
#pragma unroll
        for (int off = 1; off < 64; off <<= 1) {
            int t = __shfl_up(x, off);
            if (lane >= off) x += t;
        }
        if (base + lane < NBKT) p[base + lane] = carry + x - v;
        carry += __shfl(x, 63);
    }
}

__global__ __launch_bounds__(256) void bucket_p2(const uint2* __restrict__ ebuf,
                                                 const int* __restrict__ gcur,
                                                 const int* __restrict__ bpre,
                                                 int* __restrict__ rowptr,
                                                 int* __restrict__ srclist) {
    __shared__ unsigned img[BCAP];             // 40 KB
    __shared__ int bins[512], bst[512], cur[512], sc[256];
    const int r = blockIdx.y, b = blockIdx.x;
    const int tid = threadIdx.x;
    const int bcnt = gcur[r * NBKT + b];
    const int gbase = bpre[r * NBKT + b];
    const uint2* reg = ebuf + (size_t)(r * NBKT + b) * BCAP;
    for (int i = tid; i < 512; i += 256) bins[i] = 0;
    __syncthreads();
    for (int i = tid; i < bcnt; i += 256) atomicAdd(&bins[reg[i].y & 511], 1);
    __syncthreads();
    int v0 = bins[2 * tid], v1 = bins[2 * tid + 1];
    sc[tid] = v0 + v1;
    __syncthreads();
    for (int off = 1; off < 256; off <<= 1) {
        int t = 0;
        if (tid >= off) t = sc[tid - off];
        __syncthreads();
        sc[tid] += t;
        __syncthreads();
    }
    int base = sc[tid] - (v0 + v1);
    bst[2 * tid] = base;
    bst[2 * tid + 1] = base + v0;
    cur[2 * tid] = base;
    cur[2 * tid + 1] = base + v0;
    __syncthreads();
    for (int nl = tid; nl < 512; nl += 256) {
        int n = (b << BKT_SH) + nl;
        if (n < N) rowptr[r * (N + 1) + n] = gbase + bst[nl];
    }
    if (b == NBKT - 1 && tid == 0) rowptr[r * (N + 1) + N] = gbase + bcnt;
    for (int i = tid; i < bcnt; i += 256) {
        uint2 e = reg[i];
        int p = atomicAdd(&cur[e.y & 511], 1);
        img[p] = e.x;
    }
    __syncthreads();
    for (int i = tid; i < bcnt; i += 256) srclist[(size_t)r * E + gbase + i] = img[i];
}

// ---------------- W prep: fragment-ordered hi/lo bf16 weights ----------------

__global__ __launch_bounds__(64) void prep_wf(const float* __restrict__ W1,
                                              const float* __restrict__ W2,
                                              const float* __restrict__ Wl,
                                              short* __restrict__ WF1,
                                              short* __restrict__ WF2,
                                              short* __restrict__ WF3) {
    int f = blockIdx.x;
    int lane = threadIdx.x;
    int c = lane & 15, g = lane >> 4;
    const float* srcp;
    int stride;
    short* dstp;
    int hl;
    if (f < NF1) {
        hl = f & 1;
        int h = (f >> 1) & 1, ks = (f >> 2) & 3, tr = (f >> 4) & 3, r = f >> 6;
        int col = h * 64 + tr * 16 + c;
        srcp = W1 + (size_t)r * 128 * 128 + (size_t)(ks * 32 + g * 8) * 128 + col;
        stride = 128;
        dstp = WF1 + (size_t)f * 512 + lane * 8;
    } else if (f < NF1 + NF2) {
        int f2 = f - NF1;
        hl = f2 & 1;
        int ks = (f2 >> 1) & 3, t = f2 >> 3;
        int c192 = t * 16 + c;
        int r = c192 >> 6, col64 = c192 & 63;
        srcp = W2 + (size_t)r * 128 * 64 + (size_t)(ks * 32 + g * 8) * 64 + col64;
        stride = 64;
        dstp = WF2 + (size_t)f2 * 512 + lane * 8;
    } else {
        int f3 = f - NF1 - NF2;
        hl = f3 & 1;
        int ks = (f3 >> 1) & 1, t = f3 >> 2;
        srcp = Wl + (size_t)(ks * 32 + g * 8) * 64 + t * 16 + c;
        stride = 64;
        dstp = WF3 + (size_t)f3 * 512 + lane * 8;
    }
#pragma unroll
    for (int i = 0; i < 8; i++) {
        float v = srcp[(size_t)i * stride];
        unsigned short hi = f2bf(v);
        dstp[i] = hl ? (short)f2bf(v - __uint_as_float(((unsigned)hi) << 16)) : (short)hi;
    }
}

// ---------------- MFMA GEMM1 + fused attn logits (layer 1) ----------------
// Block = 4 waves = 64 node rows; x staged in LDS (coalesced load, padded rows).
// C/D layout: col = lane&15, row = (lane>>4)*4 + i

__device__ inline void split_a_p(const float* __restrict__ xrow, bf16x8* ah, bf16x8* al) {
#pragma unroll
    for (int ks = 0; ks < 4; ks++) {
        f32x4 xa = *(const f32x4*)(xrow + ks * 32);
        f32x4 xb = *(const f32x4*)(xrow + ks * 32 + 4);
#pragma unroll
        for (int i = 0; i < 4; i++) {
            unsigned short h = f2bf(xa[i]);
            ah[ks][i] = (short)h;
            al[ks][i] = (short)f2bf(xa[i] - __uint_as_float(((unsigned)h) << 16));
            unsigned short h2 = f2bf(xb[i]);
            ah[ks][4 + i] = (short)h2;
            al[ks][4 + i] = (short)f2bf(xb[i] - __uint_as_float(((unsigned)h2) << 16));
        }
    }
}

__global__ __launch_bounds__(256) void gemm1_mfma(const float* __restrict__ X,
                                                  const short* __restrict__ WF1,
                                                  const float* __restrict__ al1,
                                                  const float* __restrict__ ar1,
                                                  unsigned* __restrict__ packed1,
                                                  float* __restrict__ el,
                                                  float* __restrict__ er) {
    __shared__ float xs[64][132];              // 33.8 KB, +4 pad -> 2-way banks max
    const int n0_blk = blockIdx.x * 64;
    const int tid = threadIdx.x;
    const int rows = min(64, N - n0_blk);
    for (int i = tid; i < rows * 32; i += 256) {
        int row = i >> 5, q4 = i & 31;
        *(f32x4*)&xs[row][q4 * 4] = *(const f32x4*)(X + (size_t)(n0_blk + row) * K + q4 * 4);
    }
    __syncthreads();
    const int lane = tid & 63;
    const int c = lane & 15;
    const int g = lane >> 4;
    const int n0 = n0_blk + (tid >> 6) * 16;
    if (n0 >= N) return;
    bf16x8 ah[4], al[4];
    split_a_p(&xs[(tid >> 6) * 16 + c][g * 8], ah, al);
    const bf16x8* fbase = (const bf16x8*)WF1 + lane;
    for (int r = 0; r < R; r++) {
        float pel0[4] = {0.f, 0.f, 0.f, 0.f}, per0[4] = {0.f, 0.f, 0.f, 0.f};
        float pel1[4] = {0.f, 0.f, 0.f, 0.f}, per1[4] = {0.f, 0.f, 0.f, 0.f};
        for (int tr = 0; tr < 4; tr++) {
            const bf16x8* fb = fbase + (size_t)((r * 4 + tr) * 16) * 64;
            f32x4 acc0 = {0.f, 0.f, 0.f, 0.f};
            f32x4 acc1 = {0.f, 0.f, 0.f, 0.f};
#pragma unroll
            for (int ks = 0; ks < 4; ks++) {
                bf16x8 b0h = fb[(ks * 4 + 0) * 64];
                bf16x8 b0l = fb[(ks * 4 + 1) * 64];
                bf16x8 b1h = fb[(ks * 4 + 2) * 64];
                bf16x8 b1l = fb[(ks * 4 + 3) * 64];
                acc0 = __builtin_amdgcn_mfma_f32_16x16x32_bf16(ah[ks], b0h, acc0, 0, 0, 0);
                acc0 = __builtin_amdgcn_mfma_f32_16x16x32_bf16(al[ks], b0h, acc0, 0, 0, 0);
                acc0 = __builtin_amdgcn_mfma_f32_16x16x32_bf16(ah[ks], b0l, acc0, 0, 0, 0);
                acc1 = __builtin_amdgcn_mfma_f32_16x16x32_bf16(ah[ks], b1h, acc1, 0, 0, 0);
                acc1 = __builtin_amdgcn_mfma_f32_16x16x32_bf16(al[ks], b1h, acc1, 0, 0, 0);
                acc1 = __builtin_amdgcn_mfma_f32_16x16x32_bf16(ah[ks], b1l, acc1, 0, 0, 0);
            }
            float a0 = al1[r * 128 + tr * 16 + c];
            float r0 = ar1[r * 128 + tr * 16 + c];
            float a1 = al1[r * 128 + 64 + tr * 16 + c];
            float r1 = ar1[r * 128 + 64 + tr * 16 + c];
#pragma unroll
            for (int i = 0; i < 4; i++) {
                pel0[i] += acc0[i] * a0;
                per0[i] += acc0[i] * r0;
                pel1[i] += acc1[i] * a1;
                per1[i] += acc1[i] * r1;
                int m = g * 4 + i;
                unsigned wrd = (unsigned)f2bf(acc0[i]) | ((unsigned)f2bf(acc1[i]) << 16);
                packed1[(size_t)(n0 + m) * 192 + r * 64 + tr * 16 + c] = wrd;
            }
        }
#pragma unroll
        for (int off = 1; off < 16; off <<= 1) {
#pragma unroll
            for (int i = 0; i < 4; i++) {
                pel0[i] += __shfl_xor(pel0[i], off);
                per0[i] += __shfl_xor(per0[i], off);
                pel1[i] += __shfl_xor(pel1[i], off);
                per1[i] += __shfl_xor(per1[i], off);
            }
        }
        if (c == 0) {
#pragma unroll
            for (int i = 0; i < 4; i++) {
                int n = n0 + g * 4 + i;
                el[(r * N + n) * 2 + 0] = pel0[i];
                el[(r * N + n) * 2 + 1] = pel1[i];
                er[(r * N + n) * 2 + 0] = per0[i];
                er[(r * N + n) * 2 + 1] = per1[i];
            }
        }
    }
}

// ---------------- MFMA GEMM2 + fused attn logits (layer 2) ----------------

__global__ __launch_bounds__(256) void gemm2_mfma(const float* __restrict__ X,
                                                  const short* __restrict__ WF2,
                                                  const float* __restrict__ al2,
                                                  const float* __restrict__ ar2,
                                                  unsigned short* __restrict__ packed2,
                                                  float* __restrict__ el,
                                                  float* __restrict__ er) {
    __shared__ float xs[64][132];
    const int n0_blk = blockIdx.x * 64;
    const int tid = threadIdx.x;
    const int rows = min(64, N - n0_blk);
    for (int i = tid; i < rows * 32; i += 256) {
        int row = i >> 5, q4 = i & 31;
        *(f32x4*)&xs[row][q4 * 4] = *(const f32x4*)(X + (size_t)(n0_blk + row) * K + q4 * 4);
    }
    __syncthreads();
    const int lane = tid & 63;
    const int c = lane & 15;
    const int g = lane >> 4;
    const int n0 = n0_blk + (tid >> 6) * 16;
    if (n0 >= N) return;
    bf16x8 ah[4], al[4];
    split_a_p(&xs[(tid >> 6) * 16 + c][g * 8], ah, al);
    const bf16x8* fbase = (const bf16x8*)WF2 + lane;
    float pel[4], per[4];
    for (int t = 0; t < 12; t++) {
        int r = t >> 2, tt = t & 3;
        if (tt == 0) {
#pragma unroll
            for (int i = 0; i < 4; i++) { pel[i] = 0.f; per[i] = 0.f; }
        }
        f32x4 acc = {0.f, 0.f, 0.f, 0.f};
#pragma unroll
        for (int ks = 0; ks < 4; ks++) {
            bf16x8 vh = fbase[(size_t)((t * 4 + ks) * 2 + 0) * 64];
            bf16x8 vl = fbase[(size_t)((t * 4 + ks) * 2 + 1) * 64];
            acc = __builtin_amdgcn_mfma_f32_16x16x32_bf16(ah[ks], vh, acc, 0, 0, 0);
            acc = __builtin_amdgcn_mfma_f32_16x16x32_bf16(al[ks], vh, acc, 0, 0, 0);
            acc = __builtin_amdgcn_mfma_f32_16x16x32_bf16(ah[ks], vl, acc, 0, 0, 0);
        }
        float a = al2[r * 64 + tt * 16 + c];
        float rr = ar2[r * 64 + tt * 16 + c];
#pragma unroll
        for (int i = 0; i < 4; i++) {
            pel[i] += acc[i] * a;
            per[i] += acc[i] * rr;
            int m = g * 4 + i;
            packed2[(size_t)(n0 + m) * 192 + t * 16 + c] = f2bf(acc[i]);
        }
        if (tt == 3) {
#pragma unroll
            for (int off = 1; off < 16; off <<= 1) {
#pragma unroll
                for (int i = 0; i < 4; i++) {
                    pel[i] += __shfl_xor(pel[i], off);
                    per[i] += __shfl_xor(per[i], off);
                }
            }
            if (c == 0) {
#pragma unroll
                for (int i = 0; i < 4; i++) {
                    int n = n0 + g * 4 + i;
                    el[r * N + n] = pel[i];
                    er[r * N + n] = per[i];
                }
            }
        }
    }
}

// ---------------- aggregation: 4 edges/gather, u32-offset shuffles, packed FMA ----------------

__global__ __launch_bounds__(256) void agg_l1(const char* __restrict__ packed1b,
                                              const float* __restrict__ el_,
                                              const float* __restrict__ er_,
                                              const int* __restrict__ rowptr,
                                              const int* __restrict__ srclist,
                                              const float* __restrict__ b1,
                                              float* __restrict__ h1) {
    int n = (blockIdx.x * blockDim.x + threadIdx.x) >> 6;
    int lane = threadIdx.x & 63;
    if (n >= N) return;
    const int q = lane >> 4;
    const int c = lane & 15;
    const unsigned coff = (unsigned)(c * 16);
    const float2* el2 = (const float2*)el_;
    const float2* er2 = (const float2*)er_;
    float hacc0[4] = {0.f, 0.f, 0.f, 0.f}, hacc1[4] = {0.f, 0.f, 0.f, 0.f};
    for (int r = 0; r < R; r++) {
        int beg = rowptr[r * (N + 1) + n];
        int end = rowptr[r * (N + 1) + n + 1];
        float2 ern = er2[r * N + n];
        const int* sl = srclist + r * E;
        const int rbase = r * N;
        const unsigned robf = (unsigned)(r * 256);
        f32x2 acc2[4] = {{0.f, 0.f}, {0.f, 0.f}, {0.f, 0.f}, {0.f, 0.f}};
        float zl0 = 0.f, zl1 = 0.f;
        for (int cbeg = beg; cbeg < end; cbeg += 64) {
            int cnt = min(64, end - cbeg);
            unsigned ofs = 0;
            float ew0 = 0.f, ew1 = 0.f;
            if (lane < cnt) {
                int sid = sl[cbeg + lane];
                float2 e = el2[rbase + sid];
                ew0 = __expf(lrelu02(e.x + ern.x));
                ew1 = __expf(lrelu02(e.y + ern.y));
                ofs = (unsigned)sid * 768u + robf;
            }
            zl0 += ew0;
            zl1 += ew1;
            int kmax = (cnt + 3) & ~3;
            int k = 0;
            for (; k + 8 <= kmax; k += 8) {
                int iA = k + q, iB = k + 4 + q;
                unsigned oA = (unsigned)__shfl((int)ofs, iA);
                unsigned oB = (unsigned)__shfl((int)ofs, iB);
                f32x2 wA = {__shfl(ew0, iA), __shfl(ew1, iA)};
                f32x2 wB = {__shfl(ew0, iB), __shfl(ew1, iB)};
                uint4 vA = *(const uint4*)(packed1b + (oA + coff));
                uint4 vB = *(const uint4*)(packed1b + (oB + coff));
                acc2[0] += (f32x2){bf2f_lo(vA.x), bf2f_hi(vA.x)} * wA;
                acc2[1] += (f32x2){bf2f_lo(vA.y), bf2f_hi(vA.y)} * wA;
                acc2[2] += (f32x2){bf2f_lo(vA.z), bf2f_hi(vA.z)} * wA;
                acc2[3] += (f32x2){bf2f_lo(vA.w), bf2f_hi(vA.w)} * wA;
                acc2[0] += (f32x2){bf2f_lo(vB.x), bf2f_hi(vB.x)} * wB;
                acc2[1] += (f32x2){bf2f_lo(vB.y), bf2f_hi(vB.y)} * wB;
                acc2[2] += (f32x2){bf2f_lo(vB.z), bf2f_hi(vB.z)} * wB;
                acc2[3] += (f32x2){bf2f_lo(vB.w), bf2f_hi(vB.w)} * wB;
            }
            if (k < kmax) {
                int idx = k + q;
                unsigned o = (unsigned)__shfl((int)ofs, idx);
                f32x2 w = {__shfl(ew0, idx), __shfl(ew1, idx)};
                uint4 v = *(const uint4*)(packed1b + (o + coff));
                acc2[0] += (f32x2){bf2f_lo(v.x), bf2f_hi(v.x)} * w;
                acc2[1] += (f32x2){bf2f_lo(v.y), bf2f_hi(v.y)} * w;
                acc2[2] += (f32x2){bf2f_lo(v.z), bf2f_hi(v.z)} * w;
                acc2[3] += (f32x2){bf2f_lo(v.w), bf2f_hi(v.w)} * w;
            }
        }
#pragma unroll
        for (int i = 0; i < 4; i++) {
            acc2[i].x += __shfl_xor(acc2[i].x, 16);
            acc2[i].x += __shfl_xor(acc2[i].x, 32);
            acc2[i].y += __shfl_xor(acc2[i].y, 16);
            acc2[i].y += __shfl_xor(acc2[i].y, 32);
        }
#pragma unroll
        for (int off = 32; off; off >>= 1) {
            zl0 += __shfl_xor(zl0, off);
            zl1 += __shfl_xor(zl1, off);
        }
        float rz0 = (end > beg) ? __builtin_amdgcn_rcpf(zl0) : 0.f;
        float rz1 = (end > beg) ? __builtin_amdgcn_rcpf(zl1) : 0.f;
        float4 bv0 = *(const float4*)(b1 + r * 128 + c * 4);
        float4 bv1 = *(const float4*)(b1 + r * 128 + 64 + c * 4);
        hacc0[0] += elu1f(acc2[0].x * rz0 + bv0.x);
        hacc0[1] += elu1f(acc2[1].x * rz0 + bv0.y);
        hacc0[2] += elu1f(acc2[2].x * rz0 + bv0.z);
        hacc0[3] += elu1f(acc2[3].x * rz0 + bv0.w);
        hacc1[0] += elu1f(acc2[0].y * rz1 + bv1.x);
        hacc1[1] += elu1f(acc2[1].y * rz1 + bv1.y);
        hacc1[2] += elu1f(acc2[2].y * rz1 + bv1.z);
        hacc1[3] += elu1f(acc2[3].y * rz1 + bv1.w);
    }
    if (q == 0) {
        float4 o0 = {hacc0[0], hacc0[1], hacc0[2], hacc0[3]};
        float4 o1 = {hacc1[0], hacc1[1], hacc1[2], hacc1[3]};
        *(float4*)(h1 + (size_t)n * 128 + c * 4) = o0;
        *(float4*)(h1 + (size_t)n * 128 + 64 + c * 4) = o1;
    }
}

__global__ __launch_bounds__(256) void agg_l2(const char* __restrict__ packed2b,
                                              const float* __restrict__ el,
                                              const float* __restrict__ er,
                                              const int* __restrict__ rowptr,
                                              const int* __restrict__ srclist,
                                              const float* __restrict__ b2,
                                              float* __restrict__ h2) {
    int n = (blockIdx.x * blockDim.x + threadIdx.x) >> 6;
    int lane = threadIdx.x & 63;
    if (n >= N) return;
    const int q = lane >> 4;
    const int c = lane & 15;
    const unsigned coff = (unsigned)(c * 8);
    float hacc[4] = {0.f, 0.f, 0.f, 0.f};
    for (int r = 0; r < R; r++) {
        int beg = rowptr[r * (N + 1) + n];
        int end = rowptr[r * (N + 1) + n + 1];
        float ern = er[r * N + n];
        const int* sl = srclist + r * E;
        const int rbase = r * N;
        const unsigned robf = (unsigned)(r * 128);
        f32x2 acc01 = {0.f, 0.f}, acc23 = {0.f, 0.f};
        float zl = 0.f;
        for (int cbeg = beg; cbeg < end; cbeg += 64) {
            int cnt = min(64, end - cbeg);
            unsigned ofs = 0;
            float ew = 0.f;
            if (lane < cnt) {
                int sid = sl[cbeg + lane];
                ew = __expf(lrelu02(el[rbase + sid] + ern));
                ofs = (unsigned)sid * 384u + robf;
            }
            zl += ew;
            int kmax = (cnt + 3) & ~3;
            int k = 0;
            for (; k + 8 <= kmax; k += 8) {
                int iA = k + q, iB = k + 4 + q;
                unsigned oA = (unsigned)__shfl((int)ofs, iA);
                unsigned oB = (unsigned)__shfl((int)ofs, iB);
                float aA = __shfl(ew, iA), aB = __shfl(ew, iB);
                uint2 vA = *(const uint2*)(packed2b + (oA + coff));
                uint2 vB = *(const uint2*)(packed2b + (oB + coff));
                f32x2 wA = {aA, aA}, wB = {aB, aB};
                acc01 += (f32x2){bf2f_lo(vA.x), bf2f_hi(vA.x)} * wA;
                acc23 += (f32x2){bf2f_lo(vA.y), bf2f_hi(vA.y)} * wA;
                acc01 += (f32x2){bf2f_lo(vB.x), bf2f_hi(vB.x)} * wB;
                acc23 += (f32x2){bf2f_lo(vB.y), bf2f_hi(vB.y)} * wB;
            }
            if (k < kmax) {
                int idx = k + q;
                unsigned o = (unsigned)__shfl((int)ofs, idx);
                float a = __shfl(ew, idx);
                uint2 v = *(const uint2*)(packed2b + (o + coff));
                f32x2 w = {a, a};
                acc01 += (f32x2){bf2f_lo(v.x), bf2f_hi(v.x)} * w;
                acc23 += (f32x2){bf2f_lo(v.y), bf2f_hi(v.y)} * w;
            }
        }
        acc01.x += __shfl_xor(acc01.x, 16); acc01.x += __shfl_xor(acc01.x, 32);
        acc01.y += __shfl_xor(acc01.y, 16); acc01.y += __shfl_xor(acc01.y, 32);
        acc23.x += __shfl_xor(acc23.x, 16); acc23.x += __shfl_xor(acc23.x, 32);
        acc23.y += __shfl_xor(acc23.y, 16); acc23.y += __shfl_xor(acc23.y, 32);
#pragma unroll
        for (int off = 32; off; off >>= 1) zl += __shfl_xor(zl, off);
        float rz = (end > beg) ? __builtin_amdgcn_rcpf(zl) : 0.f;
        float4 bv = *(const float4*)(b2 + r * 64 + c * 4);
        hacc[0] += elu1f(acc01.x * rz + bv.x);
        hacc[1] += elu1f(acc01.y * rz + bv.y);
        hacc[2] += elu1f(acc23.x * rz + bv.z);
        hacc[3] += elu1f(acc23.y * rz + bv.w);
    }
    if (q == 0) {
        float4 o = {hacc[0], hacc[1], hacc[2], hacc[3]};
        *(float4*)(h2 + (size_t)n * 64 + c * 4) = o;
    }
}

// ---------------- MFMA GEMM3: out = h2[N,64] @ Wl[64,64] + bl ----------------

__global__ __launch_bounds__(256) void gemm3_mfma(const float* __restrict__ h2,
                                                  const short* __restrict__ WF3,
                                                  const float* __restrict__ bl,
                                                  float* __restrict__ out) {
    __shared__ float xs[64][68];               // 17.4 KB
    const int n0_blk = blockIdx.x * 64;
    const int tid = threadIdx.x;
    const int rows = min(64, N - n0_blk);
    for (int i = tid; i < rows * 16; i += 256) {
        int row = i >> 4, q4 = i & 15;
        *(f32x4*)&xs[row][q4 * 4] = *(const f32x4*)(h2 + (size_t)(n0_blk + row) * 64 + q4 * 4);
    }
    __syncthreads();
    const int lane = tid & 63;
    const int c = lane & 15;
    const int g = lane >> 4;
    const int n0 = n0_blk + (tid >> 6) * 16;
    if (n0 >= N) return;
    bf16x8 ah[2], al[2];
    const float* xrow = &xs[(tid >> 6) * 16 + c][g * 8];
#pragma unroll
    for (int ks = 0; ks < 2; ks++) {
        f32x4 xa = *(const f32x4*)(xrow + ks * 32);
        f32x4 xb = *(const f32x4*)(xrow + ks * 32 + 4);
#pragma unroll
        for (int i = 0; i < 4; i++) {
            unsigned short h = f2bf(xa[i]);
            ah[ks][i] = (short)h;
            al[ks][i] = (short)f2bf(xa[i] - __uint_as_float(((unsigned)h) << 16));
            unsigned short h2v = f2bf(xb[i]);
            ah[ks][4 + i] = (short)h2v;
            al[ks][4 + i] = (short)f2bf(xb[i] - __uint_as_float(((unsigned)h2v) << 16));
        }
    }
    const bf16x8* fbase = (const bf16x8*)WF3 + lane;
    for (int t = 0; t < 4; t++) {
        f32x4 acc = {0.f, 0.f, 0.f, 0.f};
#pragma unroll
        for (int ks = 0; ks < 2; ks++) {
            bf16x8 vh = fbase[((t * 2 + ks) * 2 + 0) * 64];
            bf16x8 vl = fbase[((t * 2 + ks) * 2 + 1) * 64];
            acc = __builtin_amdgcn_mfma_f32_16x16x32_bf16(ah[ks], vh, acc, 0, 0, 0);
            acc = __builtin_amdgcn_mfma_f32_16x16x32_bf16(al[ks], vh, acc, 0, 0, 0);
            acc = __builtin_amdgcn_mfma_f32_16x16x32_bf16(ah[ks], vl, acc, 0, 0, 0);
        }
        float bb = bl[t * 16 + c];
#pragma unroll
        for (int i = 0; i < 4; i++) {
            out[(size_t)(n0 + g * 4 + i) * 64 + t * 16 + c] = acc[i] + bb;
        }
    }
}

// ---------------- launch ----------------

extern "C" void kernel_launch(void* const* d_in, const int* in_sizes, int n_in,
                              void* d_out, int out_size, void* d_ws, size_t ws_size,
                              hipStream_t stream) {
    const float* x   = (const float*)d_in[0];
    const int*   src = (const int*)d_in[1];
    const int*   dst = (const int*)d_in[2];
    const float* W1  = (const float*)d_in[3];
    const float* al1 = (const float*)d_in[4];
    const float* ar1 = (const float*)d_in[5];
    const float* b1  = (const float*)d_in[6];
    const float* W2  = (const float*)d_in[7];
    const float* al2 = (const float*)d_in[8];
    const float* ar2 = (const float*)d_in[9];
    const float* b2  = (const float*)d_in[10];
    const float* Wl  = (const float*)d_in[11];
    const float* bl  = (const float*)d_in[12];
    float* out = (float*)d_out;

    char* ws = (char*)d_ws;
    size_t off = 0;
    auto alloc = [&](size_t bytes) {
        char* p = ws + off;
        off += (bytes + 255) & ~(size_t)255;
        return p;
    };
    unsigned*       packed1 = (unsigned*)alloc(sizeof(unsigned) * (size_t)N * R * 64);
    unsigned short* packed2 = (unsigned short*)alloc(sizeof(unsigned short) * (size_t)N * R * 64);
    float* h1      = (float*)alloc(sizeof(float) * (size_t)N * 128);
    float* h2      = (float*)alloc(sizeof(float) * (size_t)N * 64);
    float* el1     = (float*)alloc(sizeof(float) * (size_t)R * N * 2);
    float* er1     = (float*)alloc(sizeof(float) * (size_t)R * N * 2);
    float* el2     = (float*)alloc(sizeof(float) * (size_t)R * N);
    float* er2     = (float*)alloc(sizeof(float) * (size_t)R * N);
    int*   rowptr  = (int*)alloc(sizeof(int) * (size_t)R * (N + 1));
    int*   srclist = (int*)alloc(sizeof(int) * (size_t)R * E);
    uint2* ebuf    = (uint2*)alloc(sizeof(uint2) * (size_t)R * NBKT * BCAP);
    int*   gcur    = (int*)alloc(sizeof(int) * (size_t)R * NBKT);
    int*   bpre    = (int*)alloc(sizeof(int) * (size_t)R * NBKT);
    short* WF1     = (short*)alloc(sizeof(short) * (size_t)NF1 * 512);
    short* WF2     = (short*)alloc(sizeof(short) * (size_t)NF2 * 512);
    short* WF3     = (short*)alloc(sizeof(short) * (size_t)NF3 * 512);

    // --- W prep + CSR build ---
    hipMemsetAsync(gcur, 0, sizeof(int) * (size_t)R * NBKT, stream);
    prep_wf<<<NF1 + NF2 + NF3, 64, 0, stream>>>(W1, W2, Wl, WF1, WF2, WF3);
    {
        dim3 g1(P1B, R);
        bucket_p1<<<g1, 256, 0, stream>>>(src, dst, gcur, ebuf);
        bucket_scan<<<1, 192, 0, stream>>>(gcur, bpre);
        dim3 g2(NBKT, R);
        bucket_p2<<<g2, 256, 0, stream>>>(ebuf, gcur, bpre, rowptr, srclist);
    }

    // --- layer 1 ---
    gemm1_mfma<<<GB, 256, 0, stream>>>(x, WF1, al1, ar1, packed1, el1, er1);
    agg_l1<<<(N * 64 + 255) / 256, 256, 0, stream>>>((const char*)packed1, el1, er1,
                                                     rowptr, srclist, b1, h1);

    // --- layer 2 ---
    gemm2_mfma<<<GB, 256, 0, stream>>>(h1, WF2, al2, ar2, packed2, el2, er2);
    agg_l2<<<(N * 64 + 255) / 256, 256, 0, stream>>>((const char*)packed2, el2, er2,
                                                     rowptr, srclist, b2, h2);

    // --- final linear (MFMA) ---
    gemm3_mfma<<<GB, 256, 0, stream>>>(h2, WF3, bl, out);
}

// Round 12
// 277.453 us; speedup vs baseline: 1.0137x; 1.0137x over previous
//
#include <hip/hip_runtime.h>

constexpr int R = 3;
constexpr int N = 50000;
constexpr int E = 800000;
constexpr int K = 128;        // IN = HEADS*HID = 128 (both GEMM K dims)
constexpr int NT16 = N / 16;  // 3125 node-tiles for MFMA GEMMs
constexpr int GB = (NT16 + 3) / 4;  // 782 blocks of 4 tiles for GEMMs

// bucketed CSR build
constexpr int BKT_SH = 9;                    // 512 nodes per bucket
constexpr int NBKT = (N + 511) >> 9;         // 98 buckets per relation
constexpr int BCAP = 10240;                  // bucket capacity (avg 8163)
constexpr int P1E = 4096;                    // edges per pass-1 block
constexpr int P1B = (E + P1E - 1) / P1E;     // 196 blocks per relation

// fragment counts for fragment-ordered weights
constexpr int NF1 = 192;   // r(3) x tr(4) x ks(4) x head(2) x hl(2)
constexpr int NF2 = 96;    // t(12) x ks(4) x hl(2)
constexpr int NF3 = 16;    // t(4) x ks(2) x hl(2)
constexpr int PREP_BLKS = (NF1 + NF2 + NF3) / 4;  // 76 blocks x 4 frags

typedef __attribute__((ext_vector_type(8))) short bf16x8;
typedef __attribute__((ext_vector_type(4))) float f32x4;
typedef __attribute__((ext_vector_type(2))) float f32x2;

// ---------------- bf16 helpers (RNE) ----------------

__device__ inline unsigned short f2bf(float f) {
    unsigned u = __float_as_uint(f);
    u += 0x7FFF + ((u >> 16) & 1);
    return (unsigned short)(u >> 16);
}
__device__ inline float bf2f_lo(unsigned p) { return __uint_as_float(p << 16); }
__device__ inline float bf2f_hi(unsigned p) { return __uint_as_float(p & 0xFFFF0000u); }

__device__ inline float lrelu02(float x) { return fmaxf(x, 0.2f * x); }
// fast elu: exp(x)-1 instead of expm1 (error ~1e-6 abs, threshold 3.4e-3)
__device__ inline float elu1f(float x) { return x > 0.f ? x : __expf(x) - 1.f; }

// ---------------- fused A: prep_wf (fragment-ordered weights) || bucket_p1 ----------------

__device__ void prep_frag(int f, int lane,
                          const float* __restrict__ W1, const float* __restrict__ W2,
                          const float* __restrict__ Wl,
                          short* __restrict__ WF1, short* __restrict__ WF2,
                          short* __restrict__ WF3) {
    int c = lane & 15, g = lane >> 4;
    const float* srcp;
    int stride;
    short* dstp;
    int hl;
    if (f < NF1) {
        hl = f & 1;
        int h = (f >> 1) & 1, ks = (f >> 2) & 3, tr = (f >> 4) & 3, r = f >> 6;
        int col = h * 64 + tr * 16 + c;
        srcp = W1 + (size_t)r * 128 * 128 + (size_t)(ks * 32 + g * 8) * 128 + col;
        stride = 128;
        dstp = WF1 + (size_t)f * 512 + lane * 8;
    } else if (f < NF1 + NF2) {
        int f2 = f - NF1;
        hl = f2 & 1;
        int ks = (f2 >> 1) & 3, t = f2 >> 3;
        int c192 = t * 16 + c;
        int r = c192 >> 6, col64 = c192 & 63;
        srcp = W2 + (size_t)r * 128 * 64 + (size_t)(ks * 32 + g * 8) * 64 + col64;
        stride = 64;
        dstp = WF2 + (size_t)f2 * 512 + lane * 8;
    } else {
        int f3 = f - NF1 - NF2;
        hl = f3 & 1;
        int ks = (f3 >> 1) & 1, t = f3 >> 2;
        srcp = Wl + (size_t)(ks * 32 + g * 8) * 64 + t * 16 + c;
        stride = 64;
        dstp = WF3 + (size_t)f3 * 512 + lane * 8;
    }
#pragma unroll
    for (int i = 0; i < 8; i++) {
        float v = srcp[(size_t)i * stride];
        unsigned short hi = f2bf(v);
        dstp[i] = hl ? (short)f2bf(v - __uint_as_float(((unsigned)hi) << 16)) : (short)hi;
    }
}

__global__ __launch_bounds__(256) void fusedA(const int* __restrict__ src,
                                              const int* __restrict__ dst,
                                              int* __restrict__ gcur,
                                              uint2* __restrict__ ebuf,
                                              const float* __restrict__ W1,
                                              const float* __restrict__ W2,
                                              const float* __restrict__ Wl,
                                              short* __restrict__ WF1,
                                              short* __restrict__ WF2,
                                              short* __restrict__ WF3) {
    __shared__ uint2 img[P1E];                 // 32 KB (p1 path only)
    __shared__ int bins[NBKT], bstart[NBKT], gbase[NBKT];
    __shared__ int sc[128];
    const int tid = threadIdx.x;
    if (blockIdx.x < PREP_BLKS) {
        int f = blockIdx.x * 4 + (tid >> 6);
        prep_frag(f, tid & 63, W1, W2, Wl, WF1, WF2, WF3);
        return;
    }
    const int pbid = blockIdx.x - PREP_BLKS;
    const int r = pbid / P1B;
    const int e0 = (pbid % P1B) * P1E;
    const int cnt = min(P1E, E - e0);
    if (tid < NBKT) bins[tid] = 0;
    __syncthreads();
    int sv[16], dv[16], rk[16];
    int ni = 0;
    for (int i = tid; i < cnt; i += 256, ni++) {
        sv[ni] = src[(size_t)r * E + e0 + i];
        dv[ni] = dst[(size_t)r * E + e0 + i];
        rk[ni] = atomicAdd(&bins[dv[ni] >> BKT_SH], 1);
    }
    __syncthreads();
    if (tid < 128) sc[tid] = (tid < NBKT) ? bins[tid] : 0;
    __syncthreads();
    for (int off = 1; off < 128; off <<= 1) {
        int v = 0;
        if (tid < 128 && tid >= off) v = sc[tid - off];
        __syncthreads();
        if (tid < 128) sc[tid] += v;
        __syncthreads();
    }
    if (tid < NBKT) bstart[tid] = sc[tid] - bins[tid];
    __syncthreads();
    for (int j = 0; j < ni; j++) {
        int b = dv[j] >> BKT_SH;
        img[bstart[b] + rk[j]] = make_uint2((unsigned)sv[j], (unsigned)dv[j]);
    }
    if (tid < NBKT) gbase[tid] = bins[tid] ? atomicAdd(&gcur[r * NBKT + tid], bins[tid]) : 0;
    __syncthreads();
    for (int i = tid; i < cnt; i += 256) {
        uint2 e = img[i];
        int b = (int)(e.y >> BKT_SH);
        int pos = gbase[b] + (i - bstart[b]);
        if (pos < BCAP) ebuf[(size_t)(r * NBKT + b) * BCAP + pos] = e;
    }
}

// ---------------- fused B: bucket_p2 (with in-block prefix scan) || gemm1 ----------------
// C/D layout: col = lane&15, row = (lane>>4)*4 + i

__device__ inline void split_a_p(const float* __restrict__ xrow, bf16x8* ah, bf16x8* al) {
#pragma unroll
    for (int ks = 0; ks < 4; ks++) {
        f32x4 xa = *(const f32x4*)(xrow + ks * 32);
        f32x4 xb = *(const f32x4*)(xrow + ks * 32 + 4);
#pragma unroll
        for (int i = 0; i < 4; i++) {
            unsigned short h = f2bf(xa[i]);
            ah[ks][i] = (short)h;
            al[ks][i] = (short)f2bf(xa[i] - __uint_as_float(((unsigned)h) << 16));
            unsigned short h2 = f2bf(xb[i]);
            ah[ks][4 + i] = (short)h2;
            al[ks][4 + i] = (short)f2bf(xb[i] - __uint_as_float(((unsigned)h2) << 16));
        }
    }
}

__global__ __launch_bounds__(256) void fusedB(const uint2* __restrict__ ebuf,
                                              const int* __restrict__ gcur,
                                              int* __restrict__ rowptr,
                                              int* __restrict__ srclist,
                                              const float* __restrict__ X,
                                              const short* __restrict__ WF1,
                                              const float* __restrict__ al1,
                                              const float* __restrict__ ar1,
                                              unsigned* __restrict__ packed1,
                                              float* __restrict__ el,
                                              float* __restrict__ er) {
    alignas(16) __shared__ char smB[48128];    // union: p2 (48.1 KB) / gemm1 xs (33.8 KB)
    __shared__ int gbase_s;
    const int tid = threadIdx.x;
    if (blockIdx.x < R * NBKT) {
        // ---- bucket_p2 path ----
        unsigned* img = (unsigned*)smB;                     // BCAP u32 = 40960 B
        int* bins = (int*)(smB + BCAP * 4);
        int* bst = bins + 512;
        int* cur = bst + 512;
        int* sc = cur + 512;                                // 256 ints
        const int r = blockIdx.x / NBKT, b = blockIdx.x % NBKT;
        const int bcnt = gcur[r * NBKT + b];
        const uint2* reg = ebuf + (size_t)(r * NBKT + b) * BCAP;
        for (int i = tid; i < 512; i += 256) bins[i] = 0;
        if (tid < 64) {                                     // in-block prefix of gcur[r][0..b)
            int acc = 0;
            for (int base = 0; base < NBKT; base += 64) {
                int idx = base + tid;
                int v = (idx < b) ? gcur[r * NBKT + idx] : 0;
#pragma unroll
                for (int off = 32; off; off >>= 1) v += __shfl_xor(v, off);
                acc += v;
            }
            if (tid == 0) gbase_s = acc;
        }
        __syncthreads();
        const int gbase = gbase_s;
        for (int i = tid; i < bcnt; i += 256) atomicAdd(&bins[reg[i].y & 511], 1);
        __syncthreads();
        int v0 = bins[2 * tid], v1 = bins[2 * tid + 1];
        sc[tid] = v0 + v1;
        __syncthreads();
        for (int off = 1; off < 256; off <<= 1) {
            int t = 0;
            if (tid >= off) t = sc[tid - off];
            __syncthreads();
            sc[tid] += t;
            __syncthreads();
        }
        int base = sc[tid] - (v0 + v1);
        bst[2 * tid] = base;
        bst[2 * tid + 1] = base + v0;
        cur[2 * tid] = base;
        cur[2 * tid + 1] = base + v0;
        __syncthreads();
        for (int nl = tid; nl < 512; nl += 256) {
            int n = (b << BKT_SH) + nl;
            if (n < N) rowptr[r * (N + 1) + n] = gbase + bst[nl];
        }
        if (b == NBKT - 1 && tid == 0) rowptr[r * (N + 1) + N] = gbase + bcnt;
        for (int i = tid; i < bcnt; i += 256) {
            uint2 e = reg[i];
            int p = atomicAdd(&cur[e.y & 511], 1);
            img[p] = e.x;
        }
        __syncthreads();
        for (int i = tid; i < bcnt; i += 256) srclist[(size_t)r * E + gbase + i] = img[i];
        return;
    }
    // ---- gemm1 path ----
    float (*xs)[132] = (float(*)[132])smB;
    const int n0_blk = (blockIdx.x - R * NBKT) * 64;
    const int rows = min(64, N - n0_blk);
    for (int i = tid; i < rows * 32; i += 256) {
        int row = i >> 5, q4 = i & 31;
        *(f32x4*)&xs[row][q4 * 4] = *(const f32x4*)(X + (size_t)(n0_blk + row) * K + q4 * 4);
    }
    __syncthreads();
    const int lane = tid & 63;
    const int c = lane & 15;
    const int g = lane >> 4;
    const int n0 = n0_blk + (tid >> 6) * 16;
    if (n0 >= N) return;
    bf16x8 ah[4], al[4];
    split_a_p(&xs[(tid >> 6) * 16 + c][g * 8], ah, al);
    const bf16x8* fbase = (const bf16x8*)WF1 + lane;
    for (int r = 0; r < R; r++) {
        float pel0[4] = {0.f, 0.f, 0.f, 0.f}, per0[4] = {0.f, 0.f, 0.f, 0.f};
        float pel1[4] = {0.f, 0.f, 0.f, 0.f}, per1[4] = {0.f, 0.f, 0.f, 0.f};
        for (int tr = 0; tr < 4; tr++) {
            const bf16x8* fb = fbase + (size_t)((r * 4 + tr) * 16) * 64;
            f32x4 acc0 = {0.f, 0.f, 0.f, 0.f};
            f32x4 acc1 = {0.f, 0.f, 0.f, 0.f};
#pragma unroll
            for (int ks = 0; ks < 4; ks++) {
                bf16x8 b0h = fb[(ks * 4 + 0) * 64];
                bf16x8 b0l = fb[(ks * 4 + 1) * 64];
                bf16x8 b1h = fb[(ks * 4 + 2) * 64];
                bf16x8 b1l = fb[(ks * 4 + 3) * 64];
                acc0 = __builtin_amdgcn_mfma_f32_16x16x32_bf16(ah[ks], b0h, acc0, 0, 0, 0);
                acc0 = __builtin_amdgcn_mfma_f32_16x16x32_bf16(al[ks], b0h, acc0, 0, 0, 0);
                acc0 = __builtin_amdgcn_mfma_f32_16x16x32_bf16(ah[ks], b0l, acc0, 0, 0, 0);
                acc1 = __builtin_amdgcn_mfma_f32_16x16x32_bf16(ah[ks], b1h, acc1, 0, 0, 0);
                acc1 = __builtin_amdgcn_mfma_f32_16x16x32_bf16(al[ks], b1h, acc1, 0, 0, 0);
                acc1 = __builtin_amdgcn_mfma_f32_16x16x32_bf16(ah[ks], b1l, acc1, 0, 0, 0);
            }
            float a0 = al1[r * 128 + tr * 16 + c];
            float r0 = ar1[r * 128 + tr * 16 + c];
            float a1 = al1[r * 128 + 64 + tr * 16 + c];
            float r1 = ar1[r * 128 + 64 + tr * 16 + c];
#pragma unroll
            for (int i = 0; i < 4; i++) {
                pel0[i] += acc0[i] * a0;
                per0[i] += acc0[i] * r0;
                pel1[i] += acc1[i] * a1;
                per1[i] += acc1[i] * r1;
                int m = g * 4 + i;
                unsigned wrd = (unsigned)f2bf(acc0[i]) | ((unsigned)f2bf(acc1[i]) << 16);
                packed1[(size_t)(n0 + m) * 192 + r * 64 + tr * 16 + c] = wrd;
            }
        }
#pragma unroll
        for (int off = 1; off < 16; off <<= 1) {
#pragma unroll
            for (int i = 0; i < 4; i++) {
                pel0[i] += __shfl_xor(pel0[i], off);
                per0[i] += __shfl_xor(per0[i], off);
                pel1[i] += __shfl_xor(pel1[i], off);
                per1[i] += __shfl_xor(per1[i], off);
            }
        }
        if (c == 0) {
#pragma unroll
            for (int i = 0; i < 4; i++) {
                int n = n0 + g * 4 + i;
                el[(r * N + n) * 2 + 0] = pel0[i];
                el[(r * N + n) * 2 + 1] = pel1[i];
                er[(r * N + n) * 2 + 0] = per0[i];
                er[(r * N + n) * 2 + 1] = per1[i];
            }
        }
    }
}

// ---------------- MFMA GEMM2 + fused attn logits (layer 2) ----------------

__global__ __launch_bounds__(256) void gemm2_mfma(const float* __restrict__ X,
                                                  const short* __restrict__ WF2,
                                                  const float* __restrict__ al2,
                                                  const float* __restrict__ ar2,
                                                  unsigned short* __restrict__ packed2,
                                                  float* __restrict__ el,
                                                  float* __restrict__ er) {
    __shared__ float xs[64][132];
    const int n0_blk = blockIdx.x * 64;
    const int tid = threadIdx.x;
    const int rows = min(64, N - n0_blk);
    for (int i = tid; i < rows * 32; i += 256) {
        int row = i >> 5, q4 = i & 31;
        *(f32x4*)&xs[row][q4 * 4] = *(const f32x4*)(X + (size_t)(n0_blk + row) * K + q4 * 4);
    }
    __syncthreads();
    const int lane = tid & 63;
    const int c = lane & 15;
    const int g = lane >> 4;
    const int n0 = n0_blk + (tid >> 6) * 16;
    if (n0 >= N) return;
    bf16x8 ah[4], al[4];
    split_a_p(&xs[(tid >> 6) * 16 + c][g * 8], ah, al);
    const bf16x8* fbase = (const bf16x8*)WF2 + lane;
    float pel[4], per[4];
    for (int t = 0; t < 12; t++) {
        int r = t >> 2, tt = t & 3;
        if (tt == 0) {
#pragma unroll
            for (int i = 0; i < 4; i++) { pel[i] = 0.f; per[i] = 0.f; }
        }
        f32x4 acc = {0.f, 0.f, 0.f, 0.f};
#pragma unroll
        for (int ks = 0; ks < 4; ks++) {
            bf16x8 vh = fbase[(size_t)((t * 4 + ks) * 2 + 0) * 64];
            bf16x8 vl = fbase[(size_t)((t * 4 + ks) * 2 + 1) * 64];
            acc = __builtin_amdgcn_mfma_f32_16x16x32_bf16(ah[ks], vh, acc, 0, 0, 0);
            acc = __builtin_amdgcn_mfma_f32_16x16x32_bf16(al[ks], vh, acc, 0, 0, 0);
            acc = __builtin_amdgcn_mfma_f32_16x16x32_bf16(ah[ks], vl, acc, 0, 0, 0);
        }
        float a = al2[r * 64 + tt * 16 + c];
        float rr = ar2[r * 64 + tt * 16 + c];
#pragma unroll
        for (int i = 0; i < 4; i++) {
            pel[i] += acc[i] * a;
            per[i] += acc[i] * rr;
            int m = g * 4 + i;
            packed2[(size_t)(n0 + m) * 192 + t * 16 + c] = f2bf(acc[i]);
        }
        if (tt == 3) {
#pragma unroll
            for (int off = 1; off < 16; off <<= 1) {
#pragma unroll
                for (int i = 0; i < 4; i++) {
                    pel[i] += __shfl_xor(pel[i], off);
                    per[i] += __shfl_xor(per[i], off);
                }
            }
            if (c == 0) {
#pragma unroll
                for (int i = 0; i < 4; i++) {
                    int n = n0 + g * 4 + i;
                    el[r * N + n] = pel[i];
                    er[r * N + n] = per[i];
                }
            }
        }
    }
}

// ---------------- aggregation: 4 edges/gather, u32-offset shuffles, packed FMA ----------------

__global__ __launch_bounds__(256) void agg_l1(const char* __restrict__ packed1b,
                                              const float* __restrict__ el_,
                                              const float* __restrict__ er_,
                                              const int* __restrict__ rowptr,
                                              const int* __restrict__ srclist,
                                              const float* __restrict__ b1,
                                              float* __restrict__ h1) {
    int n = (blockIdx.x * blockDim.x + threadIdx.x) >> 6;
    int lane = threadIdx.x & 63;
    if (n >= N) return;
    const int q = lane >> 4;
    const int c = lane & 15;
    const unsigned coff = (unsigned)(c * 16);
    const float2* el2 = (const float2*)el_;
    const float2* er2 = (const float2*)er_;
    float hacc0[4] = {0.f, 0.f, 0.f, 0.f}, hacc1[4] = {0.f, 0.f, 0.f, 0.f};
    for (int r = 0; r < R; r++) {
        int beg = rowptr[r * (N + 1) + n];
        int end = rowptr[r * (N + 1) + n + 1];
        float2 ern = er2[r * N + n];
        const int* sl = srclist + r * E;
        const int rbase = r * N;
        const unsigned robf = (unsigned)(r * 256);
        f32x2 acc2[4] = {{0.f, 0.f}, {0.f, 0.f}, {0.f, 0.f}, {0.f, 0.f}};
        float zl0 = 0.f, zl1 = 0.f;
        for (int cbeg = beg; cbeg < end; cbeg += 64) {
            int cnt = min(64, end - cbeg);
            unsigned ofs = 0;
            float ew0 = 0.f, ew1 = 0.f;
            if (lane < cnt) {
                int sid = sl[cbeg + lane];
                float2 e = el2[rbase + sid];
                ew0 = __expf(lrelu02(e.x + ern.x));
                ew1 = __expf(lrelu02(e.y + ern.y));
                ofs = (unsigned)sid * 768u + robf;
            }
            zl0 += ew0;
            zl1 += ew1;
            int kmax = (cnt + 3) & ~3;
            int k = 0;
            for (; k + 8 <= kmax; k += 8) {
                int iA = k + q, iB = k + 4 + q;
                unsigned oA = (unsigned)__shfl((int)ofs, iA);
                unsigned oB = (unsigned)__shfl((int)ofs, iB);
                f32x2 wA = {__shfl(ew0, iA), __shfl(ew1, iA)};
                f32x2 wB = {__shfl(ew0, iB), __shfl(ew1, iB)};
                uint4 vA = *(const uint4*)(packed1b + (oA + coff));
                uint4 vB = *(const uint4*)(packed1b + (oB + coff));
                acc2[0] += (f32x2){bf2f_lo(vA.x), bf2f_hi(vA.x)} * wA;
                acc2[1] += (f32x2){bf2f_lo(vA.y), bf2f_hi(vA.y)} * wA;
                acc2[2] += (f32x2){bf2f_lo(vA.z), bf2f_hi(vA.z)} * wA;
                acc2[3] += (f32x2){bf2f_lo(vA.w), bf2f_hi(vA.w)} * wA;
                acc2[0] += (f32x2){bf2f_lo(vB.x), bf2f_hi(vB.x)} * wB;
                acc2[1] += (f32x2){bf2f_lo(vB.y), bf2f_hi(vB.y)} * wB;
                acc2[2] += (f32x2){bf2f_lo(vB.z), bf2f_hi(vB.z)} * wB;
                acc2[3] += (f32x2){bf2f_lo(vB.w), bf2f_hi(vB.w)} * wB;
            }
            if (k < kmax) {
                int idx = k + q;
                unsigned o = (unsigned)__shfl((int)ofs, idx);
                f32x2 w = {__shfl(ew0, idx), __shfl(ew1, idx)};
                uint4 v = *(const uint4*)(packed1b + (o + coff));
                acc2[0] += (f32x2){bf2f_lo(v.x), bf2f_hi(v.x)} * w;
                acc2[1] += (f32x2){bf2f_lo(v.y), bf2f_hi(v.y)} * w;
                acc2[2] += (f32x2){bf2f_lo(v.z), bf2f_hi(v.z)} * w;
                acc2[3] += (f32x2){bf2f_lo(v.w), bf2f_hi(v.w)} * w;
            }
        }
#pragma unroll
        for (int i = 0; i < 4; i++) {
            acc2[i].x += __shfl_xor(acc2[i].x, 16);
            acc2[i].x += __shfl_xor(acc2[i].x, 32);
            acc2[i].y += __shfl_xor(acc2[i].y, 16);
            acc2[i].y += __shfl_xor(acc2[i].y, 32);
        }
#pragma unroll
        for (int off = 32; off; off >>= 1) {
            zl0 += __shfl_xor(zl0, off);
            zl1 += __shfl_xor(zl1, off);
        }
        float rz0 = (end > beg) ? __builtin_amdgcn_rcpf(zl0) : 0.f;
        float rz1 = (end > beg) ? __builtin_amdgcn_rcpf(zl1) : 0.f;
        float4 bv0 = *(const float4*)(b1 + r * 128 + c * 4);
        float4 bv1 = *(const float4*)(b1 + r * 128 + 64 + c * 4);
        hacc0[0] += elu1f(acc2[0].x * rz0 + bv0.x);
        hacc0[1] += elu1f(acc2[1].x * rz0 + bv0.y);
        hacc0[2] += elu1f(acc2[2].x * rz0 + bv0.z);
        hacc0[3] += elu1f(acc2[3].x * rz0 + bv0.w);
        hacc1[0] += elu1f(acc2[0].y * rz1 + bv1.x);
        hacc1[1] += elu1f(acc2[1].y * rz1 + bv1.y);
        hacc1[2] += elu1f(acc2[2].y * rz1 + bv1.z);
        hacc1[3] += elu1f(acc2[3].y * rz1 + bv1.w);
    }
    if (q == 0) {
        float4 o0 = {hacc0[0], hacc0[1], hacc0[2], hacc0[3]};
        float4 o1 = {hacc1[0], hacc1[1], hacc1[2], hacc1[3]};
        *(float4*)(h1 + (size_t)n * 128 + c * 4) = o0;
        *(float4*)(h1 + (size_t)n * 128 + 64 + c * 4) = o1;
    }
}

__global__ __launch_bounds__(256) void agg_l2(const char* __restrict__ packed2b,
                                              const float* __restrict__ el,
                                              const float* __restrict__ er,
                                              const int* __restrict__ rowptr,
                                              const int* __restrict__ srclist,
                                              const float* __restrict__ b2,
                                              float* __restrict__ h2) {
    int n = (blockIdx.x * blockDim.x + threadIdx.x) >> 6;
    int lane = threadIdx.x & 63;
    if (n >= N) return;
    const int q = lane >> 4;
    const int c = lane & 15;
    const unsigned coff = (unsigned)(c * 8);
    float hacc[4] = {0.f, 0.f, 0.f, 0.f};
    for (int r = 0; r < R; r++) {
        int beg = rowptr[r * (N + 1) + n];
        int end = rowptr[r * (N + 1) + n + 1];
        float ern = er[r * N + n];
        const int* sl = srclist + r * E;
        const int rbase = r * N;
        const unsigned robf = (unsigned)(r * 128);
        f32x2 acc01 = {0.f, 0.f}, acc23 = {0.f, 0.f};
        float zl = 0.f;
        for (int cbeg = beg; cbeg < end; cbeg += 64) {
            int cnt = min(64, end - cbeg);
            unsigned ofs = 0;
            float ew = 0.f;
            if (lane < cnt) {
                int sid = sl[cbeg + lane];
                ew = __expf(lrelu02(el[rbase + sid] + ern));
                ofs = (unsigned)sid * 384u + robf;
            }
            zl += ew;
            int kmax = (cnt + 3) & ~3;
            int k = 0;
            for (; k + 8 <= kmax; k += 8) {
                int iA = k + q, iB = k + 4 + q;
                unsigned oA = (unsigned)__shfl((int)ofs, iA);
                unsigned oB = (unsigned)__shfl((int)ofs, iB);
                float aA = __shfl(ew, iA), aB = __shfl(ew, iB);
                uint2 vA = *(const uint2*)(packed2b + (oA + coff));
                uint2 vB = *(const uint2*)(packed2b + (oB + coff));
                f32x2 wA = {aA, aA}, wB = {aB, aB};
                acc01 += (f32x2){bf2f_lo(vA.x), bf2f_hi(vA.x)} * wA;
                acc23 += (f32x2){bf2f_lo(vA.y), bf2f_hi(vA.y)} * wA;
                acc01 += (f32x2){bf2f_lo(vB.x), bf2f_hi(vB.x)} * wB;
                acc23 += (f32x2){bf2f_lo(vB.y), bf2f_hi(vB.y)} * wB;
            }
            if (k < kmax) {
                int idx = k + q;
                unsigned o = (unsigned)__shfl((int)ofs, idx);
                float a = __shfl(ew, idx);
                uint2 v = *(const uint2*)(packed2b + (o + coff));
                f32x2 w = {a, a};
                acc01 += (f32x2){bf2f_lo(v.x), bf2f_hi(v.x)} * w;
                acc23 += (f32x2){bf2f_lo(v.y), bf2f_hi(v.y)} * w;
            }
        }
        acc01.x += __shfl_xor(acc01.x, 16); acc01.x += __shfl_xor(acc01.x, 32);
        acc01.y += __shfl_xor(acc01.y, 16); acc01.y += __shfl_xor(acc01.y, 32);
        acc23.x += __shfl_xor(acc23.x, 16); acc23.x += __shfl_xor(acc23.x, 32);
        acc23.y += __shfl_xor(acc23.y, 16); acc23.y += __shfl_xor(acc23.y, 32);
#pragma unroll
        for (int off = 32; off; off >>= 1) zl += __shfl_xor(zl, off);
        float rz = (end > beg) ? __builtin_amdgcn_rcpf(zl) : 0.f;
        float4 bv = *(const float4*)(b2 + r * 64 + c * 4);
        hacc[0] += elu1f(acc01.x * rz + bv.x);
        hacc[1] += elu1f(acc01.y * rz + bv.y);
        hacc[2] += elu1f(acc23.x * rz + bv.z);
        hacc[3] += elu1f(acc23.y * rz + bv.w);
    }
    if (q == 0) {
        float4 o = {hacc[0], hacc[1], hacc[2], hacc[3]};
        *(float4*)(h2 + (size_t)n * 64 + c * 4) = o;
    }
}

// ---------------- MFMA GEMM3: out = h2[N,64] @ Wl[64,64] + bl ----------------

__global__ __launch_bounds__(256) void gemm3_mfma(const float* __restrict__ h2,
                                                  const short* __restrict__ WF3,
                                                  const float* __restrict__ bl,
                                                  float* __restrict__ out) {
    __shared__ float xs[64][68];               // 17.4 KB
    const int n0_blk = blockIdx.x * 64;
    const int tid = threadIdx.x;
    const int rows = min(64, N - n0_blk);
    for (int i = tid; i < rows * 16; i += 256) {
        int row = i >> 4, q4 = i & 15;
        *(f32x4*)&xs[row][q4 * 4] = *(const f32x4*)(h2 + (size_t)(n0_blk + row) * 64 + q4 * 4);
    }
    __syncthreads();
    const int lane = tid & 63;
    const int c = lane & 15;
    const int g = lane >> 4;
    const int n0 = n0_blk + (tid >> 6) * 16;
    if (n0 >= N) return;
    bf16x8 ah[2], al[2];
    const float* xrow = &xs[(tid >> 6) * 16 + c][g * 8];
#pragma unroll
    for (int ks = 0; ks < 2; ks++) {
        f32x4 xa = *(const f32x4*)(xrow + ks * 32);
        f32x4 xb = *(const f32x4*)(xrow + ks * 32 + 4);
#pragma unroll
        for (int i = 0; i < 4; i++) {
            unsigned short h = f2bf(xa[i]);
            ah[ks][i] = (short)h;
            al[ks][i] = (short)f2bf(xa[i] - __uint_as_float(((unsigned)h) << 16));
            unsigned short h2v = f2bf(xb[i]);
            ah[ks][4 + i] = (short)h2v;
            al[ks][4 + i] = (short)f2bf(xb[i] - __uint_as_float(((unsigned)h2v) << 16));
        }
    }
    const bf16x8* fbase = (const bf16x8*)WF3 + lane;
    for (int t = 0; t < 4; t++) {
        f32x4 acc = {0.f, 0.f, 0.f, 0.f};
#pragma unroll
        for (int ks = 0; ks < 2; ks++) {
            bf16x8 vh = fbase[((t * 2 + ks) * 2 + 0) * 64];
            bf16x8 vl = fbase[((t * 2 + ks) * 2 + 1) * 64];
            acc = __builtin_amdgcn_mfma_f32_16x16x32_bf16(ah[ks], vh, acc, 0, 0, 0);
            acc = __builtin_amdgcn_mfma_f32_16x16x32_bf16(al[ks], vh, acc, 0, 0, 0);
            acc = __builtin_amdgcn_mfma_f32_16x16x32_bf16(ah[ks], vl, acc, 0, 0, 0);
        }
        float bb = bl[t * 16 + c];
#pragma unroll
        for (int i = 0; i < 4; i++) {
            out[(size_t)(n0 + g * 4 + i) * 64 + t * 16 + c] = acc[i] + bb;
        }
    }
}

// ---------------- launch ----------------

extern "C" void kernel_launch(void* const* d_in, const int* in_sizes, int n_in,
                              void* d_out, int out_size, void* d_ws, size_t ws_size,
                              hipStream_t stream) {
    const float* x   = (const float*)d_in[0];
    const int*   src = (const int*)d_in[1];
    const int*   dst = (const int*)d_in[2];
    const float* W1  = (const float*)d_in[3];
    const float* al1 = (const float*)d_in[4];
    const float* ar1 = (const float*)d_in[5];
    const float* b1  = (const float*)d_in[6];
    const float* W2  = (const float*)d_in[7];
    const float* al2 = (const float*)d_in[8];
    const float* ar2 = (const float*)d_in[9];
    const float* b2  = (const float*)d_in[10];
    const float* Wl  = (const float*)d_in[11];
    const float* bl  = (const float*)d_in[12];
    float* out = (float*)d_out;

    char* ws = (char*)d_ws;
    size_t off = 0;
    auto alloc = [&](size_t bytes) {
        char* p = ws + off;
        off += (bytes + 255) & ~(size_t)255;
        return p;
    };
    unsigned*       packed1 = (unsigned*)alloc(sizeof(unsigned) * (size_t)N * R * 64);
    unsigned short* packed2 = (unsigned short*)alloc(sizeof(unsigned short) * (size_t)N * R * 64);
    float* h1      = (float*)alloc(sizeof(float) * (size_t)N * 128);
    float* h2      = (float*)alloc(sizeof(float) * (size_t)N * 64);
    float* el1     = (float*)alloc(sizeof(float) * (size_t)R * N * 2);
    float* er1     = (float*)alloc(sizeof(float) * (size_t)R * N * 2);
    float* el2     = (float*)alloc(sizeof(float) * (size_t)R * N);
    float* er2     = (float*)alloc(sizeof(float) * (size_t)R * N);
    int*   rowptr  = (int*)alloc(sizeof(int) * (size_t)R * (N + 1));
    int*   srclist = (int*)alloc(sizeof(int) * (size_t)R * E);
    uint2* ebuf    = (uint2*)alloc(sizeof(uint2) * (size_t)R * NBKT * BCAP);
    int*   gcur    = (int*)alloc(sizeof(int) * (size_t)R * NBKT);
    short* WF1     = (short*)alloc(sizeof(short) * (size_t)NF1 * 512);
    short* WF2     = (short*)alloc(sizeof(short) * (size_t)NF2 * 512);
    short* WF3     = (short*)alloc(sizeof(short) * (size_t)NF3 * 512);

    hipMemsetAsync(gcur, 0, sizeof(int) * (size_t)R * NBKT, stream);

    // A: weight prep || bucket pass 1
    fusedA<<<PREP_BLKS + R * P1B, 256, 0, stream>>>(src, dst, gcur, ebuf,
                                                    W1, W2, Wl, WF1, WF2, WF3);

    // B: bucket pass 2 (in-block scan) || gemm1+logits
    fusedB<<<R * NBKT + GB, 256, 0, stream>>>(ebuf, gcur, rowptr, srclist,
                                              x, WF1, al1, ar1, packed1, el1, er1);

    // layer-1 aggregation
    agg_l1<<<(N * 64 + 255) / 256, 256, 0, stream>>>((const char*)packed1, el1, er1,
                                                     rowptr, srclist, b1, h1);

    // layer 2
    gemm2_mfma<<<GB, 256, 0, stream>>>(h1, WF2, al2, ar2, packed2, el2, er2);
    agg_l2<<<(N * 64 + 255) / 256, 256, 0, stream>>>((const char*)packed2, el2, er2,
                                                     rowptr, srclist, b2, h2);

    // final linear (MFMA)
    gemm3_mfma<<<GB, 256, 0, stream>>>(h2, WF3, bl, out);
}